// Round 1
// baseline (474.602 us; speedup 1.0000x reference)
//
#include <hip/hip_runtime.h>
#include <math.h>

typedef float f4 __attribute__((ext_vector_type(4)));
typedef float f8 __attribute__((ext_vector_type(8)));
typedef _Float16 h8 __attribute__((ext_vector_type(8)));
typedef int i4 __attribute__((ext_vector_type(4)));

// ---------------- graph build ----------------
// CSR padded per-row to a multiple of 4 edges; padding slots are (col=0, w=0)
// via pre-memset of colw. Loop then has no cleanup and i4 edge loads align.

__global__ void k_count(const int* __restrict__ dst, int* __restrict__ cnt, int E) {
  int e = blockIdx.x * blockDim.x + threadIdx.x;
  if (e < E) atomicAdd(&cnt[dst[e]], 1);
}

__global__ void k_scan_partial(const int* __restrict__ cnt, int* __restrict__ rowptr,
                               int* __restrict__ bsums, float* __restrict__ dinv, int N) {
  __shared__ int s[1024];
  int tid = threadIdx.x;
  int idx = blockIdx.x * 1024 + tid;
  int v = (idx < N) ? cnt[idx] : 0;
  if (idx < N) dinv[idx] = rsqrtf((float)(v + 1));
  int vp = (v + 3) & ~3;  // padded row capacity
  s[tid] = vp;
  __syncthreads();
  for (int off = 1; off < 1024; off <<= 1) {
    int add = (tid >= off) ? s[tid - off] : 0;
    __syncthreads();
    s[tid] += add;
    __syncthreads();
  }
  if (idx <= N) rowptr[idx] = s[tid] - vp;
  if (tid == 1023) bsums[blockIdx.x] = s[1023];
}

__global__ void k_scan_sums(int* __restrict__ bsums, int nb) {
  __shared__ int s[1024];
  int tid = threadIdx.x;
  int v = (tid < nb) ? bsums[tid] : 0;
  s[tid] = v;
  __syncthreads();
  for (int off = 1; off < 1024; off <<= 1) {
    int add = (tid >= off) ? s[tid - off] : 0;
    __syncthreads();
    s[tid] += add;
    __syncthreads();
  }
  if (tid < nb) bsums[tid] = s[tid] - v;
}

__global__ void k_add_offsets(int* __restrict__ rowptr, int* __restrict__ cursor,
                              const int* __restrict__ bsums, int N) {
  int idx = blockIdx.x * 1024 + threadIdx.x;
  if (idx <= N) {
    int v = rowptr[idx] + bsums[blockIdx.x];
    rowptr[idx] = v;
    if (idx < N) cursor[idx] = v;
  }
}

__global__ void k_scatter(const int* __restrict__ src, const int* __restrict__ dst,
                          const float* __restrict__ dinv, int* __restrict__ cursor,
                          int2* __restrict__ colw, int E) {
  int e = blockIdx.x * blockDim.x + threadIdx.x;
  if (e < E) {
    int s = src[e];
    int d = dst[e];
    int slot = atomicAdd(&cursor[d], 1);
    colw[slot] = make_int2(s, __float_as_int(dinv[s] * dinv[d]));
  }
}

__global__ void k_tohalf(const float* __restrict__ x, _Float16* __restrict__ xh, int total8) {
  int i = blockIdx.x * blockDim.x + threadIdx.x;
  if (i < total8) {
    f4 a = ((const f4*)x)[i * 2], b = ((const f4*)x)[i * 2 + 1];
    f8 v = {a.x, a.y, a.z, a.w, b.x, b.y, b.z, b.w};
    ((h8*)xh)[i] = __builtin_convertvector(v, h8);
  }
}

// ---------------- diffusion (Horner): y <- gs*(A_hat y_in) + c_j xh ----------
// 2 rows per wave. grp (0..7): row = grp>>2, half = (grp>>1)&1, part = grp&1.
// Each (row,half) is served by TWO 8-lane groups taking alternate edge-quads
// (stride 8), each running 4 gather chains -> 8 chains in flight per row-half,
// combined at the end with one shfl_xor(8). Streaming traffic (colw, xh,
// yout) is non-temporal so the per-XCD L2 keeps the random gather set (y_in).
__global__ __launch_bounds__(256) void k_hop(
    const int* __restrict__ rowptr, const int2* __restrict__ colw,
    const float* __restrict__ dinv, const h8* __restrict__ xh,
    const h8* __restrict__ yin, h8* __restrict__ yout,
    const float* __restrict__ t_ptr, int j, int first, int N) {
  int wave = threadIdx.x >> 6;
  int lane = threadIdx.x & 63;
  int grp = lane >> 3;
  int part = grp & 1;
  int r = (blockIdx.x * 4 + wave) * 2 + (grp >> 2);
  if (r >= N) return;
  int fl = (lane & 7) + ((grp >> 1) & 1) * 8;  // h8 slot 0..15 within the row
  float t = t_ptr[0];
  float cj = expf(-t);
  for (int i = 1; i <= j; ++i) cj *= t / (float)i;
  float gs = first ? cj * t / (float)(j + 1) : 1.0f;

  auto G = [&](int idx) -> f8 {
    return __builtin_convertvector(yin[(size_t)idx * 16 + fl], f8);
  };

  // hoisted independent loads (issued only by part 0; overlap the edge loop)
  float di = 0.f;
  f8 selfv = {0, 0, 0, 0, 0, 0, 0, 0};
  f8 xr = selfv;
  if (!part) {
    di = dinv[r];
    selfv = G(r);
    xr = __builtin_convertvector(__builtin_nontemporal_load(&xh[(size_t)r * 16 + fl]), f8);
  }

  f8 sA = {0, 0, 0, 0, 0, 0, 0, 0}, sB = sA, sC = sA, sD = sA;
  const i4* cw = (const i4*)colw;
  int e = rowptr[r] + (part << 2);
  int end = rowptr[r + 1];  // row capacity is a multiple of 4
  if (e < end) {
    i4 p0 = __builtin_nontemporal_load(&cw[e >> 1]);
    i4 p1 = __builtin_nontemporal_load(&cw[(e >> 1) + 1]);
    for (e += 8; e < end; e += 8) {
      i4 q0 = __builtin_nontemporal_load(&cw[e >> 1]);
      i4 q1 = __builtin_nontemporal_load(&cw[(e >> 1) + 1]);
      sA += __int_as_float(p0.y) * G(p0.x);
      sB += __int_as_float(p0.w) * G(p0.z);
      sC += __int_as_float(p1.y) * G(p1.x);
      sD += __int_as_float(p1.w) * G(p1.z);
      p0 = q0;
      p1 = q1;
    }
    sA += __int_as_float(p0.y) * G(p0.x);
    sB += __int_as_float(p0.w) * G(p0.z);
    sC += __int_as_float(p1.y) * G(p1.x);
    sD += __int_as_float(p1.w) * G(p1.z);
  }
  f8 s = (sA + sB) + (sC + sD);
#pragma unroll
  for (int k = 0; k < 8; ++k) s[k] += __shfl_xor(s[k], 8, 64);

  if (!part) {
    s += (di * di) * selfv;  // self-loop source = y_in[r] (xh on first hop)
    s = gs * s + cj * xr;
    __builtin_nontemporal_store(__builtin_convertvector(s, h8),
                                &yout[(size_t)r * 16 + fl]);
  }
}

// ---------------- epilogue: out = y16 @ W^T + b (MFMA fp16, W = hi+lo) ------
// W staged as fp16 hi/lo in LDS (2x32 KB), XOR-granule swizzle; A-frags read
// straight from global y16. fp32 accumulate; W-quant error ~2^-22 (exact).
__global__ __launch_bounds__(256) void k_matmul(
    const h8* __restrict__ y16, const float* __restrict__ W,
    const float* __restrict__ bias, float* __restrict__ out, int N) {
  __shared__ h8 whiS[128 * 16];
  __shared__ h8 wloS[128 * 16];
  int tid = threadIdx.x;
  int rblk = blockIdx.x * 128;

#pragma unroll
  for (int it = 0; it < 8; ++it) {
    int idx = it * 256 + tid;
    int n = idx >> 4, g = idx & 15;
    f4 a = *(const f4*)&W[(size_t)n * 128 + g * 8];
    f4 b = *(const f4*)&W[(size_t)n * 128 + g * 8 + 4];
    f8 w = {a.x, a.y, a.z, a.w, b.x, b.y, b.z, b.w};
    h8 hi = __builtin_convertvector(w, h8);
    f8 hir = __builtin_convertvector(hi, f8);
    h8 lo = __builtin_convertvector(w - hir, h8);
    int slot = n * 16 + (g ^ (n & 7));
    whiS[slot] = hi;
    wloS[slot] = lo;
  }
  __syncthreads();

  int wave = tid >> 6, lane = tid & 63;
  int q = lane >> 4, fl = lane & 15;
  int rbase = rblk + wave * 32;

  f4 acc[2][8];
#pragma unroll
  for (int rt = 0; rt < 2; ++rt)
#pragma unroll
    for (int nt = 0; nt < 8; ++nt) acc[rt][nt] = (f4){0.f, 0.f, 0.f, 0.f};

#pragma unroll
  for (int s = 0; s < 4; ++s) {
    h8 aA, aB;
    {
      int r0 = rbase + fl;       if (r0 >= N) r0 = N - 1;
      int r1 = rbase + 16 + fl;  if (r1 >= N) r1 = N - 1;
      aA = __builtin_nontemporal_load(&y16[(size_t)r0 * 16 + s * 4 + q]);
      aB = __builtin_nontemporal_load(&y16[(size_t)r1 * 16 + s * 4 + q]);
    }
#pragma unroll
    for (int nt = 0; nt < 8; ++nt) {
      int n = nt * 16 + fl;
      int slot = n * 16 + ((s * 4 + q) ^ (n & 7));
      h8 bh = whiS[slot];
      h8 bl = wloS[slot];
      acc[0][nt] = __builtin_amdgcn_mfma_f32_16x16x32_f16(aA, bh, acc[0][nt], 0, 0, 0);
      acc[0][nt] = __builtin_amdgcn_mfma_f32_16x16x32_f16(aA, bl, acc[0][nt], 0, 0, 0);
      acc[1][nt] = __builtin_amdgcn_mfma_f32_16x16x32_f16(aB, bh, acc[1][nt], 0, 0, 0);
      acc[1][nt] = __builtin_amdgcn_mfma_f32_16x16x32_f16(aB, bl, acc[1][nt], 0, 0, 0);
    }
  }

#pragma unroll
  for (int rt = 0; rt < 2; ++rt) {
#pragma unroll
    for (int nt = 0; nt < 8; ++nt) {
      float bv = bias[nt * 16 + fl];
#pragma unroll
      for (int reg = 0; reg < 4; ++reg) {
        int r = rbase + rt * 16 + q * 4 + reg;
        if (r < N) {
          float v = acc[rt][nt][reg] + bv;
          __builtin_nontemporal_store(v, &out[(size_t)r * 128 + nt * 16 + fl]);
        }
      }
    }
  }
}

// ---------------- launch ----------------

extern "C" void kernel_launch(void* const* d_in, const int* in_sizes, int n_in,
                              void* d_out, int out_size, void* d_ws, size_t ws_size,
                              hipStream_t stream) {
  const float* x = (const float*)d_in[0];
  const int* ei = (const int*)d_in[1];   // int32! (harness converts integer inputs)
  const float* t = (const float*)d_in[2];
  const float* W = (const float*)d_in[3];
  const float* b = (const float*)d_in[4];
  int N = in_sizes[0] / 128;
  int E = in_sizes[1] / 2;
  const int* srcp = ei;
  const int* dstp = ei + E;
  float* out = (float*)d_out;

  char* ws = (char*)d_ws;
  size_t off = 0;
  auto alloc = [&](size_t bytes) -> void* {
    void* p = ws + off;
    off += (bytes + 255) & ~(size_t)255;
    return p;
  };
  h8*    yh0    = (h8*)alloc((size_t)N * 128 * 2);  // fp16 ping
  h8*    yh1    = (h8*)alloc((size_t)N * 128 * 2);  // fp16 pong
  h8*    xh     = (h8*)alloc((size_t)N * 128 * 2);  // fp16 x
  int*   cnt    = (int*)alloc((size_t)N * 4);
  float* dinv   = (float*)alloc((size_t)N * 4);
  int*   rowptr = (int*)alloc((size_t)(N + 1) * 4);
  int*   cursor = (int*)alloc((size_t)N * 4);
  int*   bsums  = (int*)alloc(4096);
  size_t colw_bytes = ((size_t)E + 4 * (size_t)N) * 8;  // padded-CSR upper bound
  int2*  colw   = (int2*)alloc(colw_bytes);
  (void)ws_size;  // ~46 MB total

  int nb_scan = (N + 1 + 1023) / 1024;

  hipMemsetAsync(cnt, 0, (size_t)N * 4, stream);
  hipMemsetAsync(colw, 0, colw_bytes, stream);  // padding slots: col=0, w=0
  k_count<<<(E + 255) / 256, 256, 0, stream>>>(dstp, cnt, E);
  k_scan_partial<<<nb_scan, 1024, 0, stream>>>(cnt, rowptr, bsums, dinv, N);
  k_scan_sums<<<1, 1024, 0, stream>>>(bsums, nb_scan);
  k_add_offsets<<<nb_scan, 1024, 0, stream>>>(rowptr, cursor, bsums, N);
  k_scatter<<<(E + 255) / 256, 256, 0, stream>>>(srcp, dstp, dinv, cursor, colw, E);
  k_tohalf<<<(N * 16 + 255) / 256, 256, 0, stream>>>(x, (_Float16*)xh, N * 16);

  // Horner: y <- A_hat y + c_j x, j = 9..0; first hop gathers xh with gs=c10.
  int nblk = (N + 7) / 8;  // 8 rows per 256-thread block (2 per wave)
  const h8* yin = xh;
  h8* bufs[2] = {yh0, yh1};
  for (int m = 0; m < 10; ++m) {
    h8* yout = bufs[m & 1];
    k_hop<<<nblk, 256, 0, stream>>>(rowptr, colw, dinv, xh, yin, yout,
                                    t, 9 - m, (m == 0) ? 1 : 0, N);
    yin = yout;
  }

  k_matmul<<<(N + 127) / 128, 256, 0, stream>>>(yin, W, b, out, N);
}

// Round 2
// 440.381 us; speedup vs baseline: 1.0777x; 1.0777x over previous
//
#include <hip/hip_runtime.h>
#include <math.h>

typedef float f4 __attribute__((ext_vector_type(4)));
typedef float f8 __attribute__((ext_vector_type(8)));
typedef _Float16 h8 __attribute__((ext_vector_type(8)));
typedef int i4 __attribute__((ext_vector_type(4)));

// ---------------- graph build ----------------
// CSR padded per-row to a multiple of 4 edges; padding slots are (col=0, w=0)
// via pre-memset of colw. Loop then has no cleanup and i4 edge loads align.

__global__ void k_count(const int* __restrict__ dst, int* __restrict__ cnt, int E) {
  int e = blockIdx.x * blockDim.x + threadIdx.x;
  if (e < E) atomicAdd(&cnt[dst[e]], 1);
}

__global__ void k_scan_partial(const int* __restrict__ cnt, int* __restrict__ rowptr,
                               int* __restrict__ bsums, float* __restrict__ dinv, int N) {
  __shared__ int s[1024];
  int tid = threadIdx.x;
  int idx = blockIdx.x * 1024 + tid;
  int v = (idx < N) ? cnt[idx] : 0;
  if (idx < N) dinv[idx] = rsqrtf((float)(v + 1));
  int vp = (v + 3) & ~3;  // padded row capacity
  s[tid] = vp;
  __syncthreads();
  for (int off = 1; off < 1024; off <<= 1) {
    int add = (tid >= off) ? s[tid - off] : 0;
    __syncthreads();
    s[tid] += add;
    __syncthreads();
  }
  if (idx <= N) rowptr[idx] = s[tid] - vp;
  if (tid == 1023) bsums[blockIdx.x] = s[1023];
}

__global__ void k_scan_sums(int* __restrict__ bsums, int nb) {
  __shared__ int s[1024];
  int tid = threadIdx.x;
  int v = (tid < nb) ? bsums[tid] : 0;
  s[tid] = v;
  __syncthreads();
  for (int off = 1; off < 1024; off <<= 1) {
    int add = (tid >= off) ? s[tid - off] : 0;
    __syncthreads();
    s[tid] += add;
    __syncthreads();
  }
  if (tid < nb) bsums[tid] = s[tid] - v;
}

__global__ void k_add_offsets(int* __restrict__ rowptr, int* __restrict__ cursor,
                              const int* __restrict__ bsums, int N) {
  int idx = blockIdx.x * 1024 + threadIdx.x;
  if (idx <= N) {
    int v = rowptr[idx] + bsums[blockIdx.x];
    rowptr[idx] = v;
    if (idx < N) cursor[idx] = v;
  }
}

__global__ void k_scatter(const int* __restrict__ src, const int* __restrict__ dst,
                          const float* __restrict__ dinv, int* __restrict__ cursor,
                          int2* __restrict__ colw, int E) {
  int e = blockIdx.x * blockDim.x + threadIdx.x;
  if (e < E) {
    int s = src[e];
    int d = dst[e];
    int slot = atomicAdd(&cursor[d], 1);
    colw[slot] = make_int2(s, __float_as_int(dinv[s] * dinv[d]));
  }
}

__global__ void k_tohalf(const float* __restrict__ x, _Float16* __restrict__ xh, int total8) {
  int i = blockIdx.x * blockDim.x + threadIdx.x;
  if (i < total8) {
    f4 a = ((const f4*)x)[i * 2], b = ((const f4*)x)[i * 2 + 1];
    f8 v = {a.x, a.y, a.z, a.w, b.x, b.y, b.z, b.w};
    ((h8*)xh)[i] = __builtin_convertvector(v, h8);
  }
}

// ---------------- diffusion (Horner): y <- gs*(A_hat y_in) + c_j xh ----------
// 8 groups of 8 lanes per wave: group g -> row (g>>1), feature-half (g&1).
// Edge loop unrolled to 8 edges/iter: 8 independent gather chains in flight
// per group, colw quads for the NEXT iteration prefetched one iter ahead so
// the colw->gather address dependency is off the critical path.
__global__ __launch_bounds__(256) void k_hop(
    const int* __restrict__ rowptr, const int2* __restrict__ colw,
    const float* __restrict__ dinv, const h8* __restrict__ xh,
    const h8* __restrict__ yin, h8* __restrict__ yout,
    const float* __restrict__ t_ptr, int j, int first, int N) {
  int wave = threadIdx.x >> 6;
  int lane = threadIdx.x & 63;
  int grp = lane >> 3;
  int r = (blockIdx.x * 4 + wave) * 4 + (grp >> 1);
  if (r >= N) return;
  int fl = (lane & 7) + (grp & 1) * 8;  // h8 slot 0..15 within the row
  float t = t_ptr[0];
  float cj = expf(-t);
  for (int i = 1; i <= j; ++i) cj *= t / (float)i;
  float gs = first ? cj * t / (float)(j + 1) : 1.0f;

  auto G = [&](int idx) -> f8 {
    return __builtin_convertvector(yin[(size_t)idx * 16 + fl], f8);
  };

  f8 sA = {0, 0, 0, 0, 0, 0, 0, 0}, sB = sA, sC = sA, sD = sA;
  int e = rowptr[r], end = rowptr[r + 1];  // end-e is a multiple of 4
  int cnt = end - e;
  const i4* q = (const i4*)&colw[e];  // one i4 = 2 edges
  int it8 = cnt >> 3;                 // 8-edge iterations
  int tail4 = cnt & 7;                // 0 or 4 leftover edges

  i4 p0 = {0, 0, 0, 0}, p1 = p0, p2 = p0, p3 = p0;
  if (it8) {
    p0 = q[0]; p1 = q[1]; p2 = q[2]; p3 = q[3];
    q += 4;
  }
  for (int i = 1; i < it8; ++i) {
    i4 n0 = q[0], n1 = q[1], n2 = q[2], n3 = q[3];  // prefetch next 8 edges
    q += 4;
    f8 g0 = G(p0.x), g1 = G(p0.z), g2 = G(p1.x), g3 = G(p1.z);
    f8 g4 = G(p2.x), g5 = G(p2.z), g6 = G(p3.x), g7 = G(p3.z);
    sA += __int_as_float(p0.y) * g0;
    sB += __int_as_float(p0.w) * g1;
    sC += __int_as_float(p1.y) * g2;
    sD += __int_as_float(p1.w) * g3;
    sA += __int_as_float(p2.y) * g4;
    sB += __int_as_float(p2.w) * g5;
    sC += __int_as_float(p3.y) * g6;
    sD += __int_as_float(p3.w) * g7;
    p0 = n0; p1 = n1; p2 = n2; p3 = n3;
  }
  if (it8) {  // drain the last prefetched 8 edges
    f8 g0 = G(p0.x), g1 = G(p0.z), g2 = G(p1.x), g3 = G(p1.z);
    f8 g4 = G(p2.x), g5 = G(p2.z), g6 = G(p3.x), g7 = G(p3.z);
    sA += __int_as_float(p0.y) * g0;
    sB += __int_as_float(p0.w) * g1;
    sC += __int_as_float(p1.y) * g2;
    sD += __int_as_float(p1.w) * g3;
    sA += __int_as_float(p2.y) * g4;
    sB += __int_as_float(p2.w) * g5;
    sC += __int_as_float(p3.y) * g6;
    sD += __int_as_float(p3.w) * g7;
  }
  if (tail4) {  // remaining 4 edges (row capacity is a multiple of 4)
    i4 a0 = q[0], a1 = q[1];
    f8 g0 = G(a0.x), g1 = G(a0.z), g2 = G(a1.x), g3 = G(a1.z);
    sA += __int_as_float(a0.y) * g0;
    sB += __int_as_float(a0.w) * g1;
    sC += __int_as_float(a1.y) * g2;
    sD += __int_as_float(a1.w) * g3;
  }

  f8 s = (sA + sB) + (sC + sD);
  float di = dinv[r];
  s += (di * di) * G(r);  // self-loop source = y_in[r] (xh on first hop)
  f8 xr = __builtin_convertvector(xh[(size_t)r * 16 + fl], f8);
  s = gs * s + cj * xr;
  yout[(size_t)r * 16 + fl] = __builtin_convertvector(s, h8);
}

// ---------------- epilogue: out = y16 @ W^T + b (MFMA fp16, W = hi+lo) ------
// W staged as fp16 hi/lo in LDS (2x32 KB), XOR-granule swizzle; A-frags read
// straight from global y16. fp32 accumulate; W-quant error ~2^-22 (exact).
__global__ __launch_bounds__(256) void k_matmul(
    const h8* __restrict__ y16, const float* __restrict__ W,
    const float* __restrict__ bias, float* __restrict__ out, int N) {
  __shared__ h8 whiS[128 * 16];
  __shared__ h8 wloS[128 * 16];
  int tid = threadIdx.x;
  int rblk = blockIdx.x * 128;

#pragma unroll
  for (int it = 0; it < 8; ++it) {
    int idx = it * 256 + tid;
    int n = idx >> 4, g = idx & 15;
    f4 a = *(const f4*)&W[(size_t)n * 128 + g * 8];
    f4 b = *(const f4*)&W[(size_t)n * 128 + g * 8 + 4];
    f8 w = {a.x, a.y, a.z, a.w, b.x, b.y, b.z, b.w};
    h8 hi = __builtin_convertvector(w, h8);
    f8 hir = __builtin_convertvector(hi, f8);
    h8 lo = __builtin_convertvector(w - hir, h8);
    int slot = n * 16 + (g ^ (n & 7));
    whiS[slot] = hi;
    wloS[slot] = lo;
  }
  __syncthreads();

  int wave = tid >> 6, lane = tid & 63;
  int q = lane >> 4, fl = lane & 15;
  int rbase = rblk + wave * 32;

  f4 acc[2][8];
#pragma unroll
  for (int rt = 0; rt < 2; ++rt)
#pragma unroll
    for (int nt = 0; nt < 8; ++nt) acc[rt][nt] = (f4){0.f, 0.f, 0.f, 0.f};

#pragma unroll
  for (int s = 0; s < 4; ++s) {
    h8 aA, aB;
    {
      int r0 = rbase + fl;       if (r0 >= N) r0 = N - 1;
      int r1 = rbase + 16 + fl;  if (r1 >= N) r1 = N - 1;
      aA = y16[(size_t)r0 * 16 + s * 4 + q];
      aB = y16[(size_t)r1 * 16 + s * 4 + q];
    }
#pragma unroll
    for (int nt = 0; nt < 8; ++nt) {
      int n = nt * 16 + fl;
      int slot = n * 16 + ((s * 4 + q) ^ (n & 7));
      h8 bh = whiS[slot];
      h8 bl = wloS[slot];
      acc[0][nt] = __builtin_amdgcn_mfma_f32_16x16x32_f16(aA, bh, acc[0][nt], 0, 0, 0);
      acc[0][nt] = __builtin_amdgcn_mfma_f32_16x16x32_f16(aA, bl, acc[0][nt], 0, 0, 0);
      acc[1][nt] = __builtin_amdgcn_mfma_f32_16x16x32_f16(aB, bh, acc[1][nt], 0, 0, 0);
      acc[1][nt] = __builtin_amdgcn_mfma_f32_16x16x32_f16(aB, bl, acc[1][nt], 0, 0, 0);
    }
  }

#pragma unroll
  for (int rt = 0; rt < 2; ++rt) {
#pragma unroll
    for (int nt = 0; nt < 8; ++nt) {
      float bv = bias[nt * 16 + fl];
#pragma unroll
      for (int reg = 0; reg < 4; ++reg) {
        int r = rbase + rt * 16 + q * 4 + reg;
        if (r < N) out[(size_t)r * 128 + nt * 16 + fl] = acc[rt][nt][reg] + bv;
      }
    }
  }
}

// ---------------- launch ----------------

extern "C" void kernel_launch(void* const* d_in, const int* in_sizes, int n_in,
                              void* d_out, int out_size, void* d_ws, size_t ws_size,
                              hipStream_t stream) {
  const float* x = (const float*)d_in[0];
  const int* ei = (const int*)d_in[1];   // int32! (harness converts integer inputs)
  const float* t = (const float*)d_in[2];
  const float* W = (const float*)d_in[3];
  const float* b = (const float*)d_in[4];
  int N = in_sizes[0] / 128;
  int E = in_sizes[1] / 2;
  const int* srcp = ei;
  const int* dstp = ei + E;
  float* out = (float*)d_out;

  char* ws = (char*)d_ws;
  size_t off = 0;
  auto alloc = [&](size_t bytes) -> void* {
    void* p = ws + off;
    off += (bytes + 255) & ~(size_t)255;
    return p;
  };
  h8*    yh0    = (h8*)alloc((size_t)N * 128 * 2);  // fp16 ping
  h8*    yh1    = (h8*)alloc((size_t)N * 128 * 2);  // fp16 pong
  h8*    xh     = (h8*)alloc((size_t)N * 128 * 2);  // fp16 x
  int*   cnt    = (int*)alloc((size_t)N * 4);
  float* dinv   = (float*)alloc((size_t)N * 4);
  int*   rowptr = (int*)alloc((size_t)(N + 1) * 4);
  int*   cursor = (int*)alloc((size_t)N * 4);
  int*   bsums  = (int*)alloc(4096);
  size_t colw_bytes = ((size_t)E + 4 * (size_t)N) * 8;  // padded-CSR upper bound
  int2*  colw   = (int2*)alloc(colw_bytes);
  (void)ws_size;  // ~46 MB total

  int nb_scan = (N + 1 + 1023) / 1024;

  hipMemsetAsync(cnt, 0, (size_t)N * 4, stream);
  hipMemsetAsync(colw, 0, colw_bytes, stream);  // padding slots: col=0, w=0
  k_count<<<(E + 255) / 256, 256, 0, stream>>>(dstp, cnt, E);
  k_scan_partial<<<nb_scan, 1024, 0, stream>>>(cnt, rowptr, bsums, dinv, N);
  k_scan_sums<<<1, 1024, 0, stream>>>(bsums, nb_scan);
  k_add_offsets<<<nb_scan, 1024, 0, stream>>>(rowptr, cursor, bsums, N);
  k_scatter<<<(E + 255) / 256, 256, 0, stream>>>(srcp, dstp, dinv, cursor, colw, E);
  k_tohalf<<<(N * 16 + 255) / 256, 256, 0, stream>>>(x, (_Float16*)xh, N * 16);

  // Horner: y <- A_hat y + c_j x, j = 9..0; first hop gathers xh with gs=c10.
  int nblk = (N + 15) / 16;  // 16 rows per 256-thread block (4 per wave)
  const h8* yin = xh;
  h8* bufs[2] = {yh0, yh1};
  for (int m = 0; m < 10; ++m) {
    h8* yout = bufs[m & 1];
    k_hop<<<nblk, 256, 0, stream>>>(rowptr, colw, dinv, xh, yin, yout,
                                    t, 9 - m, (m == 0) ? 1 : 0, N);
    yin = yout;
  }

  k_matmul<<<(N + 127) / 128, 256, 0, stream>>>(yin, W, b, out, N);
}

// Round 3
// 429.242 us; speedup vs baseline: 1.1057x; 1.0260x over previous
//
#include <hip/hip_runtime.h>
#include <math.h>

typedef float f4 __attribute__((ext_vector_type(4)));
typedef float f8 __attribute__((ext_vector_type(8)));
typedef _Float16 h8 __attribute__((ext_vector_type(8)));
typedef int i4 __attribute__((ext_vector_type(4)));

// ---------------- graph build ----------------
// CSR padded per-row to a multiple of 4 edges. Edges store ONLY the source
// column (4 B): the symmetric normalization dinv[s]*dinv[d] is factored out
// by keeping the iterate in the scaled domain z = dinv .* y. Padding slots
// point at sentinel row N, which is kept all-zero in every gather buffer.

__global__ void k_count(const int* __restrict__ dst, int* __restrict__ cnt, int E) {
  int e = blockIdx.x * blockDim.x + threadIdx.x;
  if (e < E) atomicAdd(&cnt[dst[e]], 1);
}

__global__ void k_scan_partial(const int* __restrict__ cnt, int* __restrict__ rowptr,
                               int* __restrict__ bsums, float* __restrict__ dinv,
                               float* __restrict__ rdinv, int N) {
  __shared__ int s[1024];
  int tid = threadIdx.x;
  int idx = blockIdx.x * 1024 + tid;
  int v = (idx < N) ? cnt[idx] : 0;
  if (idx < N) {
    dinv[idx] = rsqrtf((float)(v + 1));
    rdinv[idx] = sqrtf((float)(v + 1));
  }
  int vp = (v + 3) & ~3;  // padded row capacity
  s[tid] = vp;
  __syncthreads();
  for (int off = 1; off < 1024; off <<= 1) {
    int add = (tid >= off) ? s[tid - off] : 0;
    __syncthreads();
    s[tid] += add;
    __syncthreads();
  }
  if (idx <= N) rowptr[idx] = s[tid] - vp;
  if (tid == 1023) bsums[blockIdx.x] = s[1023];
}

__global__ void k_scan_sums(int* __restrict__ bsums, int nb) {
  __shared__ int s[1024];
  int tid = threadIdx.x;
  int v = (tid < nb) ? bsums[tid] : 0;
  s[tid] = v;
  __syncthreads();
  for (int off = 1; off < 1024; off <<= 1) {
    int add = (tid >= off) ? s[tid - off] : 0;
    __syncthreads();
    s[tid] += add;
    __syncthreads();
  }
  if (tid < nb) bsums[tid] = s[tid] - v;
}

__global__ void k_add_offsets(int* __restrict__ rowptr, int* __restrict__ cursor,
                              const int* __restrict__ bsums, int N) {
  int idx = blockIdx.x * 1024 + threadIdx.x;
  if (idx <= N) {
    int v = rowptr[idx] + bsums[blockIdx.x];
    rowptr[idx] = v;
    if (idx < N) cursor[idx] = v;
  }
}

__global__ void k_scatter(const int* __restrict__ src, const int* __restrict__ dst,
                          int* __restrict__ cursor, int* __restrict__ col, int E) {
  int e = blockIdx.x * blockDim.x + threadIdx.x;
  if (e < E) {
    int d = dst[e];
    int slot = atomicAdd(&cursor[d], 1);
    col[slot] = src[e];
  }
}

// fill padding slots (cursor[r]..rowptr[r+1]) with sentinel row N
__global__ void k_padfill(const int* __restrict__ rowptr, const int* __restrict__ cursor,
                          int* __restrict__ col, int N) {
  int r = blockIdx.x * blockDim.x + threadIdx.x;
  if (r < N) {
    int e = cursor[r], end = rowptr[r + 1];
    for (; e < end; ++e) col[e] = N;
  }
}

// xz = fp16(dinv .* x); also zero sentinel row N of xz, z0, z1
__global__ void k_tohalf(const float* __restrict__ x, _Float16* __restrict__ xz,
                         const float* __restrict__ dinv, _Float16* __restrict__ z0,
                         _Float16* __restrict__ z1, int total8) {
  int i = blockIdx.x * blockDim.x + threadIdx.x;
  if (i < total8) {
    float d = dinv[i >> 4];
    f4 a = ((const f4*)x)[i * 2], b = ((const f4*)x)[i * 2 + 1];
    f8 v = {a.x, a.y, a.z, a.w, b.x, b.y, b.z, b.w};
    ((h8*)xz)[i] = __builtin_convertvector(d * v, h8);
  } else if (i < total8 + 48) {
    int k = i - total8;
    h8 zero = {0, 0, 0, 0, 0, 0, 0, 0};
    if (k < 16) ((h8*)xz)[total8 + k] = zero;
    else if (k < 32) ((h8*)z0)[total8 + (k - 16)] = zero;
    else ((h8*)z1)[total8 + (k - 32)] = zero;
  }
}

// ---------------- diffusion (Horner, z-domain) ------------------------------
// z_out[r] = gs*dinv[r]^2*(sum_e z_in[col_e] + z_in[r]) + c_j*xz[r]
// 8 groups of 8 lanes per wave: group g -> row (g>>1), feature-half (g&1).
// 8 edges/iter (2 i4 col loads, prefetched one iter ahead), 8 gather chains.
__global__ __launch_bounds__(256) void k_hop(
    const int* __restrict__ rowptr, const int* __restrict__ col,
    const float* __restrict__ dinv, const h8* __restrict__ xz,
    const h8* __restrict__ zin, h8* __restrict__ zout,
    const float* __restrict__ t_ptr, int j, int first, int N) {
  int wave = threadIdx.x >> 6;
  int lane = threadIdx.x & 63;
  int grp = lane >> 3;
  int r = (blockIdx.x * 4 + wave) * 4 + (grp >> 1);
  if (r >= N) return;
  int fl = (lane & 7) + (grp & 1) * 8;  // h8 slot 0..15 within the row
  float t = t_ptr[0];
  float cj = expf(-t);
  for (int i = 1; i <= j; ++i) cj *= t / (float)i;
  float gs = first ? cj * t / (float)(j + 1) : 1.0f;

  auto G = [&](int idx) -> f8 {
    return __builtin_convertvector(zin[(size_t)idx * 16 + fl], f8);
  };

  f8 sA = {0, 0, 0, 0, 0, 0, 0, 0}, sB = sA, sC = sA, sD = sA;
  int e = rowptr[r], end = rowptr[r + 1];  // end-e is a multiple of 4
  int cnt = end - e;
  const i4* q = (const i4*)&col[e];  // one i4 = 4 edges
  int it8 = cnt >> 3;                // 8-edge iterations
  int tail4 = cnt & 7;               // 0 or 4 leftover edges

  i4 p0 = {0, 0, 0, 0}, p1 = p0;
  if (it8) {
    p0 = q[0]; p1 = q[1];
    q += 2;
  }
  for (int i = 1; i < it8; ++i) {
    i4 n0 = q[0], n1 = q[1];  // prefetch next 8 edges
    q += 2;
    sA += G(p0.x);
    sB += G(p0.y);
    sC += G(p0.z);
    sD += G(p0.w);
    sA += G(p1.x);
    sB += G(p1.y);
    sC += G(p1.z);
    sD += G(p1.w);
    p0 = n0; p1 = n1;
  }
  if (it8) {  // drain the last prefetched 8 edges
    sA += G(p0.x);
    sB += G(p0.y);
    sC += G(p0.z);
    sD += G(p0.w);
    sA += G(p1.x);
    sB += G(p1.y);
    sC += G(p1.z);
    sD += G(p1.w);
  }
  if (tail4) {  // remaining 4 edges
    i4 a0 = q[0];
    sA += G(a0.x);
    sB += G(a0.y);
    sC += G(a0.z);
    sD += G(a0.w);
  }

  f8 s = (sA + sB) + (sC + sD);
  s += G(r);  // + z_in[r] (self-loop, normalization folded into dinv^2)
  float di = dinv[r];
  float sc = gs * di * di;
  f8 xr = __builtin_convertvector(xz[(size_t)r * 16 + fl], f8);
  s = sc * s + cj * xr;
  zout[(size_t)r * 16 + fl] = __builtin_convertvector(s, h8);
}

// ---------------- epilogue: out = (rdinv .* z) @ W^T + b (MFMA fp16) --------
// W staged as fp16 hi/lo in LDS (2x32 KB), XOR-granule swizzle; A-frags read
// straight from global z16. The rdinv un-scaling is applied to the fp32
// accumulators (exact, no extra fp16 rounding). fp32 accumulate.
__global__ __launch_bounds__(256) void k_matmul(
    const h8* __restrict__ z16, const float* __restrict__ W,
    const float* __restrict__ bias, const float* __restrict__ rdinv,
    float* __restrict__ out, int N) {
  __shared__ h8 whiS[128 * 16];
  __shared__ h8 wloS[128 * 16];
  int tid = threadIdx.x;
  int rblk = blockIdx.x * 128;

#pragma unroll
  for (int it = 0; it < 8; ++it) {
    int idx = it * 256 + tid;
    int n = idx >> 4, g = idx & 15;
    f4 a = *(const f4*)&W[(size_t)n * 128 + g * 8];
    f4 b = *(const f4*)&W[(size_t)n * 128 + g * 8 + 4];
    f8 w = {a.x, a.y, a.z, a.w, b.x, b.y, b.z, b.w};
    h8 hi = __builtin_convertvector(w, h8);
    f8 hir = __builtin_convertvector(hi, f8);
    h8 lo = __builtin_convertvector(w - hir, h8);
    int slot = n * 16 + (g ^ (n & 7));
    whiS[slot] = hi;
    wloS[slot] = lo;
  }
  __syncthreads();

  int wave = tid >> 6, lane = tid & 63;
  int q = lane >> 4, fl = lane & 15;
  int rbase = rblk + wave * 32;

  f4 acc[2][8];
#pragma unroll
  for (int rt = 0; rt < 2; ++rt)
#pragma unroll
    for (int nt = 0; nt < 8; ++nt) acc[rt][nt] = (f4){0.f, 0.f, 0.f, 0.f};

#pragma unroll
  for (int s = 0; s < 4; ++s) {
    h8 aA, aB;
    {
      int r0 = rbase + fl;       if (r0 >= N) r0 = N - 1;
      int r1 = rbase + 16 + fl;  if (r1 >= N) r1 = N - 1;
      aA = z16[(size_t)r0 * 16 + s * 4 + q];
      aB = z16[(size_t)r1 * 16 + s * 4 + q];
    }
#pragma unroll
    for (int nt = 0; nt < 8; ++nt) {
      int n = nt * 16 + fl;
      int slot = n * 16 + ((s * 4 + q) ^ (n & 7));
      h8 bh = whiS[slot];
      h8 bl = wloS[slot];
      acc[0][nt] = __builtin_amdgcn_mfma_f32_16x16x32_f16(aA, bh, acc[0][nt], 0, 0, 0);
      acc[0][nt] = __builtin_amdgcn_mfma_f32_16x16x32_f16(aA, bl, acc[0][nt], 0, 0, 0);
      acc[1][nt] = __builtin_amdgcn_mfma_f32_16x16x32_f16(aB, bh, acc[1][nt], 0, 0, 0);
      acc[1][nt] = __builtin_amdgcn_mfma_f32_16x16x32_f16(aB, bl, acc[1][nt], 0, 0, 0);
    }
  }

#pragma unroll
  for (int rt = 0; rt < 2; ++rt) {
#pragma unroll
    for (int reg = 0; reg < 4; ++reg) {
      int r = rbase + rt * 16 + q * 4 + reg;
      if (r < N) {
        float rd = rdinv[r];
#pragma unroll
        for (int nt = 0; nt < 8; ++nt) {
          out[(size_t)r * 128 + nt * 16 + fl] =
              acc[rt][nt][reg] * rd + bias[nt * 16 + fl];
        }
      }
    }
  }
}

// ---------------- launch ----------------

extern "C" void kernel_launch(void* const* d_in, const int* in_sizes, int n_in,
                              void* d_out, int out_size, void* d_ws, size_t ws_size,
                              hipStream_t stream) {
  const float* x = (const float*)d_in[0];
  const int* ei = (const int*)d_in[1];   // int32! (harness converts integer inputs)
  const float* t = (const float*)d_in[2];
  const float* W = (const float*)d_in[3];
  const float* b = (const float*)d_in[4];
  int N = in_sizes[0] / 128;
  int E = in_sizes[1] / 2;
  const int* srcp = ei;
  const int* dstp = ei + E;
  float* out = (float*)d_out;

  char* ws = (char*)d_ws;
  size_t off = 0;
  auto alloc = [&](size_t bytes) -> void* {
    void* p = ws + off;
    off += (bytes + 255) & ~(size_t)255;
    return p;
  };
  h8*    zh0    = (h8*)alloc((size_t)(N + 1) * 128 * 2);  // fp16 z ping (+sentinel)
  h8*    zh1    = (h8*)alloc((size_t)(N + 1) * 128 * 2);  // fp16 z pong (+sentinel)
  h8*    xz     = (h8*)alloc((size_t)(N + 1) * 128 * 2);  // fp16 dinv.*x (+sentinel)
  int*   cnt    = (int*)alloc((size_t)N * 4);
  float* dinv   = (float*)alloc((size_t)N * 4);
  float* rdinv  = (float*)alloc((size_t)N * 4);
  int*   rowptr = (int*)alloc((size_t)(N + 1) * 4);
  int*   cursor = (int*)alloc((size_t)N * 4);
  int*   bsums  = (int*)alloc(4096);
  size_t col_bytes = ((size_t)E + 4 * (size_t)N) * 4;  // padded-CSR upper bound
  int*   col    = (int*)alloc(col_bytes);
  (void)ws_size;  // ~43 MB total

  int nb_scan = (N + 1 + 1023) / 1024;

  hipMemsetAsync(cnt, 0, (size_t)N * 4, stream);
  k_count<<<(E + 255) / 256, 256, 0, stream>>>(dstp, cnt, E);
  k_scan_partial<<<nb_scan, 1024, 0, stream>>>(cnt, rowptr, bsums, dinv, rdinv, N);
  k_scan_sums<<<1, 1024, 0, stream>>>(bsums, nb_scan);
  k_add_offsets<<<nb_scan, 1024, 0, stream>>>(rowptr, cursor, bsums, N);
  k_scatter<<<(E + 255) / 256, 256, 0, stream>>>(srcp, dstp, cursor, col, E);
  k_padfill<<<(N + 255) / 256, 256, 0, stream>>>(rowptr, cursor, col, N);
  k_tohalf<<<(N * 16 + 48 + 255) / 256, 256, 0, stream>>>(x, (_Float16*)xz, dinv,
                                                          (_Float16*)zh0, (_Float16*)zh1,
                                                          N * 16);

  // Horner: z <- gs*dinv^2*(A z + z) + c_j xz, j = 9..0; first hop gathers xz.
  int nblk = (N + 15) / 16;  // 16 rows per 256-thread block (4 per wave)
  const h8* zin = xz;
  h8* bufs[2] = {zh0, zh1};
  for (int m = 0; m < 10; ++m) {
    h8* zout = bufs[m & 1];
    k_hop<<<nblk, 256, 0, stream>>>(rowptr, col, dinv, xz, zin, zout,
                                    t, 9 - m, (m == 0) ? 1 : 0, N);
    zin = zout;
  }

  k_matmul<<<(N + 127) / 128, 256, 0, stream>>>(zin, W, b, rdinv, out, N);
}